// Round 4
// baseline (591.218 us; speedup 1.0000x reference)
//
#include <hip/hip_runtime.h>

// Problem constants (from reference)
#define NB      128
#define ND      8
#define NK      8
#define TLEN    512
#define NSTEPS  496

#define INVLN2f 1.44269504088896340736f

__device__ __forceinline__ float fexp(float x) { return __expf(x); }
__device__ __forceinline__ float flog(float x) { return __logf(x); }
__device__ __forceinline__ float frcp(float x) { return __builtin_amdgcn_rcpf(x); }
__device__ __forceinline__ float elur(float x) { return x > 0.f ? x : fexp(x) - 1.f; }

#if defined(__has_builtin)
#if __has_builtin(__builtin_amdgcn_exp2f)
#define fexp2(x) __builtin_amdgcn_exp2f(x)
#endif
#endif
#ifndef fexp2
#define fexp2(x) exp2f(x)
#endif

// DPP helpers. quad_perm 0xB1 = lane^1, 0x4E = lane^2, row_ror:4 acts as lane^4
// within a replicated-every-8 value; row_ror:N (0x120|N) rotates within 16-lane rows.
#define DPP_ROR4(v) __int_as_float(__builtin_amdgcn_mov_dpp(__float_as_int(v), 0x124, 0xF, 0xF, false))
#define DPP_X1(v)   __int_as_float(__builtin_amdgcn_mov_dpp(__float_as_int(v), 0xB1, 0xF, 0xF, false))
#define DPP_X2(v)   __int_as_float(__builtin_amdgcn_mov_dpp(__float_as_int(v), 0x4E, 0xF, 0xF, false))
#define DPP_RORN(v, ctrl) __int_as_float(__builtin_amdgcn_mov_dpp(__float_as_int(v), (ctrl), 0xF, 0xF, false))

#define RED8_MAX(m) { m = fmaxf(m, DPP_X1(m)); m = fmaxf(m, DPP_X2(m)); m = fmaxf(m, DPP_ROR4(m)); }
#define RED8_SUM(s) { s = s + DPP_X1(s); s = s + DPP_X2(s); s = s + DPP_ROR4(s); }

typedef unsigned int uint2v __attribute__((ext_vector_type(2)));
typedef float floatx2 __attribute__((ext_vector_type(2)));

__device__ __forceinline__ floatx2 f2(float t) { floatx2 r; r.x = t; r.y = t; return r; }

#if defined(__has_builtin)
#if __has_builtin(__builtin_amdgcn_permlane32_swap)
#define HAVE_PLSWAP 1
#endif
#if __has_builtin(__builtin_amdgcn_permlane16_swap)
#define HAVE_PL16SWAP 1
#endif
#endif

#ifdef HAVE_PLSWAP
__device__ __forceinline__ float xhalfsum(float v) {
    unsigned int u = __float_as_uint(v);
    uint2v r = __builtin_amdgcn_permlane32_swap(u, u, false, false);
    return __uint_as_float(r[0]) + __uint_as_float(r[1]);
}
#else
__device__ __forceinline__ float xhalfsum(float v) { return v + __shfl_xor(v, 32); }
#endif

// Layout-B fixup: rows 0,1 (lanes 0-31) keep own value; rows 2,3 take lane^16's.
#ifdef HAVE_PL16SWAP
#define TOB(v) ({                                                                  \
    float _v = (v);                                                                \
    unsigned _u = __float_as_uint(_v);                                             \
    uint2v _r = __builtin_amdgcn_permlane16_swap(_u, _u, false, false);            \
    float _o = __uint_as_float(selr0 ? _r[0] : _r[1]);                             \
    (lane < 32) ? _v : _o; })
#else
#define TOB(v) ({                                                                  \
    float _v = (v);                                                                \
    float _o = __uint_as_float((unsigned)__builtin_amdgcn_ds_swizzle(              \
                   (int)__float_as_uint(_v), 0x401F));                             \
    (lane < 32) ? _v : _o; })
#endif

// Dual 16-term rotation dot (new-tap in .x, old-tap in .y).
__device__ __forceinline__ floatx2 rotdot16x2p(float vB, const floatx2* __restrict__ wp) {
    float t1 = DPP_RORN(vB, 0x121), t2 = DPP_RORN(vB, 0x122), t3 = DPP_RORN(vB, 0x123);
    float t4 = DPP_RORN(vB, 0x124), t5 = DPP_RORN(vB, 0x125), t6 = DPP_RORN(vB, 0x126);
    float t7 = DPP_RORN(vB, 0x127), t8 = DPP_RORN(vB, 0x128), t9 = DPP_RORN(vB, 0x129);
    float tA = DPP_RORN(vB, 0x12A), tB = DPP_RORN(vB, 0x12B), tC = DPP_RORN(vB, 0x12C);
    float tD = DPP_RORN(vB, 0x12D), tE = DPP_RORN(vB, 0x12E), tF = DPP_RORN(vB, 0x12F);
    floatx2 a0 = wp[0] * f2(vB);
    floatx2 a1 = wp[1] * f2(t1);
    floatx2 a2 = wp[2] * f2(t2);
    floatx2 a3 = wp[3] * f2(t3);
    a0 = __builtin_elementwise_fma(wp[4],  f2(t4), a0);
    a1 = __builtin_elementwise_fma(wp[5],  f2(t5), a1);
    a2 = __builtin_elementwise_fma(wp[6],  f2(t6), a2);
    a3 = __builtin_elementwise_fma(wp[7],  f2(t7), a3);
    a0 = __builtin_elementwise_fma(wp[8],  f2(t8), a0);
    a1 = __builtin_elementwise_fma(wp[9],  f2(t9), a1);
    a2 = __builtin_elementwise_fma(wp[10], f2(tA), a2);
    a3 = __builtin_elementwise_fma(wp[11], f2(tB), a3);
    a0 = __builtin_elementwise_fma(wp[12], f2(tC), a0);
    a1 = __builtin_elementwise_fma(wp[13], f2(tD), a1);
    a2 = __builtin_elementwise_fma(wp[14], f2(tE), a2);
    a3 = __builtin_elementwise_fma(wp[15], f2(tF), a3);
    return (a0 + a1) + (a2 + a3);
}

// Critical-wave step for chain SFX (A or B). Two chains share weights; their
// instruction streams are independent so the in-order SIMD fills one chain's
// dependency stalls with the other chain's work. Feedback sum S uses a 3-level
// add tree over the rt rotations (already needed for the z-dot) instead of a
// serial butterfly: -3 cross-lane hops on the critical chain.
#define STEPP(SFX, qv, S1, S2, S3, DO_OUT, XPEXPR)                                \
  {                                                                               \
    const int q_ = (qv);                                                          \
    float o0v = elur(XZ##SFX);                                                    \
    float v0B = TOB(o0v);                                                         \
    floatx2 d1 = rotdot16x2p(v0B, w1p);                                           \
    float o1v = elur(xhalfsum(d1.x + P1##SFX[S1]));                               \
    P1##SFX[S1] = b1h + d1.y;                                                     \
    float v1B = TOB(o1v);                                                         \
    floatx2 d2 = rotdot16x2p(v1B, w2p);                                           \
    float o2v = elur(xhalfsum(d2.x + P2##SFX[S2]));                               \
    P2##SFX[S2] = b2h + d2.y;                                                     \
    float v2B = TOB(o2v);                                                         \
    floatx2 d3 = rotdot16x2p(v2B, w3p);                                           \
    float a3m = elur(xhalfsum(d3.x + P3##SFX[S3]));                               \
    P3##SFX[S3] = b3h + d3.y;                                                     \
    if (DO_OUT) {                                                                 \
      amr##SFX[((q_) & 15) * 64 + lane] = a3m;                                    \
      float g2_own = xgg##SFX[((((q_) - 15) >> 6) & 1) * 512                      \
                              + (((q_) - 15) & 63) * 8 + o3];                     \
      float F = fexp2(fmaf(a3m, klog, g2_own));                                   \
      float rt1 = DPP_RORN(F, 0x121), rt2 = DPP_RORN(F, 0x122);                   \
      float rt3 = DPP_RORN(F, 0x123), rt4 = DPP_RORN(F, 0x124);                   \
      float rt5 = DPP_RORN(F, 0x125), rt6 = DPP_RORN(F, 0x126);                   \
      float rt7 = DPP_RORN(F, 0x127);                                             \
      float S = ((F + rt1) + (rt2 + rt3)) + ((rt4 + rt5) + (rt6 + rt7));          \
      float r2 = frcp(S);                                                         \
      float na = wznrot[0] * F,   nb = wznrot[1] * rt1;                           \
      float nc = wznrot[2] * rt2, nd = wznrot[3] * rt3;                           \
      na = fmaf(wznrot[4], rt4, na); nb = fmaf(wznrot[5], rt5, nb);               \
      nc = fmaf(wznrot[6], rt6, nc); nd = fmaf(wznrot[7], rt7, nd);               \
      float oa = wzorot[0] * F,   ob = wzorot[1] * rt1;                           \
      float oc = wzorot[2] * rt2, od = wzorot[3] * rt3;                           \
      oa = fmaf(wzorot[4], rt4, oa); ob = fmaf(wzorot[5], rt5, ob);               \
      oc = fmaf(wzorot[6], rt6, oc); od = fmaf(wzorot[7], rt7, od);               \
      ZN##SFX   = ((na + nb) + (nc + nd)) * r2;                                   \
      ZQ2n##SFX = ((oa + ob) + (oc + od)) * r2;                                   \
    }                                                                             \
    XZ##SFX = ((XPEXPR) + ZQ2##SFX) + ZN##SFX;                                    \
    ZQ2##SFX = ZQ2n##SFX;                                                         \
  }

// Helper-wave output step: recompute F (bit-identical inputs and op order to
// the critical wave's feedback) + log-softmax; do the global stores.
#define ROLEA(pv, amr, xgg, zoffv, qoffv)                                         \
  {                                                                               \
    const int p_ = (pv);                                                          \
    float a3 = (amr)[((p_) & 15) * 64 + lane];                                    \
    float g2 = (xgg)[(((p_ - 15) >> 6) & 1) * 512 + ((p_ - 15) & 63) * 8 + o3];   \
    float F = fexp2(fmaf(a3, klog, g2));                                          \
    float rt1 = DPP_RORN(F, 0x121), rt2 = DPP_RORN(F, 0x122);                     \
    float rt3 = DPP_RORN(F, 0x123), rt4 = DPP_RORN(F, 0x124);                     \
    float rt5 = DPP_RORN(F, 0x125), rt6 = DPP_RORN(F, 0x126);                     \
    float rt7 = DPP_RORN(F, 0x127);                                               \
    float S = ((F + rt1) + (rt2 + rt3)) + ((rt4 + rt5) + (rt6 + rt7));            \
    float r2 = frcp(S);                                                           \
    float mx = a3; RED8_MAX(mx);                                                  \
    float e = fexp(a3 - mx);                                                      \
    float se = e; RED8_SUM(se);                                                   \
    float lse = mx + flog(se);                                                    \
    if (lane < 8) {                                                               \
      outg[(zoffv) + lane * TLEN + p_ + 1]       = F * r2;                        \
      outg[(qoffv) + lane * NSTEPS + (p_ - 15)]  = a3 - lse;                      \
    }                                                                             \
  }

__global__ __launch_bounds__(128, 1)
void regime_scan_kernel(const float* __restrict__ xg,
                        const float* __restrict__ tempg,
                        const float* __restrict__ ug,
                        const float* __restrict__ w0g,
                        const float* __restrict__ b0g,
                        const float* __restrict__ w1g,
                        const float* __restrict__ b1g,
                        const float* __restrict__ w2g,
                        const float* __restrict__ b2g,
                        const float* __restrict__ w3g,
                        const float* __restrict__ b3g,
                        float* __restrict__ outg)
{
    __shared__ __align__(16) float xring[2][80 * 8];     // 5 KB  (helper private)
    __shared__ __align__(16) float XGx[2][2][64][32];    // 32 KB: XP(q), chunk dbuf
    __shared__ __align__(16) float XGg[2][2][64][8];     // 8 KB: g2(q), chunk dbuf
    __shared__ __align__(16) float XPwarm[2][15][32];    // XP(1..14) per batch
    __shared__ __align__(16) float amring[2][16][64];    // a3m handoff rings

    const int lane = threadIdx.x & 63;
    const int wid  = threadIdx.x >> 6;
    const int bA   = blockIdx.x * 2;
    const int bB   = bA + 1;
    const int c    = lane & 31;
    const int o3   = lane & 7;
    const int tap  = (lane < 32) ? 1 : 0;
    const int s    = lane & 15;
    const int rowq = lane >> 4;
    const int jbase = ((rowq ^ (rowq >> 1)) & 1) << 4;

    // runtime probes
    int dir;
    {
        int l15 = lane & 15;
        int rr1 = __builtin_amdgcn_mov_dpp(l15, 0x121, 0xF, 0xF, false);
        dir = (rr1 == ((l15 + 1) & 15)) ? 1 : -1;
    }
    int selr0 = 0;
#ifdef HAVE_PL16SWAP
    {
        unsigned li = (unsigned)lane;
        uint2v pr = __builtin_amdgcn_permlane16_swap(li, li, false, false);
        selr0 = (pr[0] == (li ^ 16u)) ? 1 : 0;
    }
#endif
    (void)s; (void)jbase; (void)dir; (void)selr0;

    const float tinv = frcp(tempg[0]);
    const float klog = tinv * INVLN2f;

    if (wid == 0) {
        // ================= critical wave: chains A and B =================
        float wznrot[8], wzorot[8];
        #pragma unroll
        for (int r = 0; r < 8; ++r) {
            int ch = (o3 + dir * r) & 7;
            wznrot[r] = w0g[c * 32 + (8 + ch) * 2 + 1];
            wzorot[r] = w0g[c * 32 + (8 + ch) * 2 + 0];
        }
        floatx2 w1p[16], w2p[16], w3p[16];
        #pragma unroll
        for (int r = 0; r < 16; ++r) {
            int jj = jbase + ((s + dir * r) & 15);
            w1p[r].x = w1g[c  * 64 + jj * 2 + 1];
            w1p[r].y = w1g[c  * 64 + jj * 2 + 0];
            w2p[r].x = w2g[c  * 64 + jj * 2 + 1];
            w2p[r].y = w2g[c  * 64 + jj * 2 + 0];
            w3p[r].x = w3g[o3 * 64 + jj * 2 + 1];
            w3p[r].y = w3g[o3 * 64 + jj * 2 + 0];
        }
        const float b1h = 0.5f * b1g[c];
        const float b2h = 0.5f * b2g[c];
        const float b3h = 0.5f * b3g[o3];

        const float* xgxA = &XGx[0][0][0][0];
        const float* xgxB = &XGx[1][0][0][0];
        const float* xggA = &XGg[0][0][0][0];
        const float* xggB = &XGg[1][0][0][0];
        float* amrA = &amring[0][0][0];
        float* amrB = &amring[1][0][0];

        __syncthreads();   // barrier0: helper prologue fills done

        float P1A[2] = { b1h, b1h }, P1B[2] = { b1h, b1h };
        float P2A[4] = { b2h, b2h, b2h, b2h }, P2B[4] = { b2h, b2h, b2h, b2h };
        float P3A[8], P3B[8];
        #pragma unroll
        for (int k = 0; k < 8; ++k) { P3A[k] = b3h; P3B[k] = b3h; }
        float ZQ2A = 0.f, ZQ2nA = 0.f, ZNA = 0.f;
        float ZQ2B = 0.f, ZQ2nB = 0.f, ZNB = 0.f;
        float XZA = XPwarm[0][1][c];
        float XZB = XPwarm[1][1][c];

        // warmup q=1..14 (no outputs, feedback zero)
        #pragma unroll
        for (int q = 1; q <= 14; ++q) {
            STEPP(A, q, q & 1, q & 3, q & 7, 0,
                  (q < 14 ? XPwarm[0][q + 1][c] : xgxA[c]));
            STEPP(B, q, q & 1, q & 3, q & 7, 0,
                  (q < 14 ? XPwarm[1][q + 1][c] : xgxB[c]));
        }
        __syncthreads();   // warmup barrier

        // main: 62 blocks of 8 steps x 2 chains, one barrier per block
        for (int j = 0; j < 62; ++j) {
            const int qb = 15 + 8 * j;
            #pragma unroll
            for (int u = 0; u < 8; ++u) {
                STEPP(A, qb + u, (15 + u) & 1, (15 + u) & 3, (15 + u) & 7, 1,
                      xgxA[((((qb + u) - 14) >> 6) & 1) * 2048
                           + (((qb + u) - 14) & 63) * 32 + c]);
                STEPP(B, qb + u, (15 + u) & 1, (15 + u) & 3, (15 + u) & 7, 1,
                      xgxB[((((qb + u) - 14) >> 6) & 1) * 2048
                           + (((qb + u) - 14) & 63) * 32 + c]);
            }
            __syncthreads();
        }
    } else {
        // ================= helper wave: both batches =================
        float wxr[8];
        #pragma unroll
        for (int d = 0; d < 8; ++d) wxr[d] = w0g[c * 32 + d * 2 + tap];
        const float b0r = b0g[c];
        const float* xbp[2]  = { xg + bA * (ND * TLEN), xg + bB * (ND * TLEN) };
        const int    zoffs[2] = { bA * (NK * TLEN), bB * (NK * TLEN) };
        const int    qoffs[2] = { NB * NK * TLEN + bA * (NK * NSTEPS),
                                  NB * NK * TLEN + bB * (NK * NSTEPS) };

        for (int bi = 0; bi < 2; ++bi) {
            const float* xb = xbp[bi];
            // x ring cols 0..79 (l == col)
            for (int idx = lane; idx < 80 * ND; idx += 64) {
                int l = idx >> 3, d = idx & 7;
                int t = l - 15;
                xring[bi][idx] = (t >= 0) ? xb[d * TLEN + t] : 0.f;
            }
            // XP(1..14) -> XPwarm; XP(15..78) -> XGx[bi][0]
            for (int it = 0; it <= 77; ++it) {
                const float4* xq = (const float4*)&xring[bi][(it + tap) * 8];
                float4 xa = xq[0], xbv = xq[1];
                float s0 = fmaf(wxr[0], xa.x, fmaf(wxr[1], xa.y, 0.f));
                float s1 = fmaf(wxr[2], xa.z, fmaf(wxr[3], xa.w, 0.f));
                float s2 = fmaf(wxr[4], xbv.x, fmaf(wxr[5], xbv.y, 0.f));
                float s3 = fmaf(wxr[6], xbv.z, fmaf(wxr[7], xbv.w, 0.f));
                float h = xhalfsum((s0 + s1) + (s2 + s3)) + b0r;
                if (lane < 32) {
                    if (it < 14) XPwarm[bi][it + 1][c] = h;
                    else         XGx[bi][0][it - 14][c] = h;
                }
            }
            // g2 chunk 0 (steps 0..63)
            for (int idx = lane; idx < 64 * NK; idx += 64) {
                int st = idx >> 3, kk = idx & 7;
                float uu = ug[st * (NB * NK) + (bA + bi) * NK + kk];
                XGg[bi][0][idx >> 3][kk] = -flog(-flog(uu + 1e-10f) + 1e-10f) * klog;
            }
            // z_all[:, :, 0:16] = 0
            for (int idx = lane; idx < NK * 16; idx += 64) {
                outg[zoffs[bi] + (idx >> 4) * TLEN + (idx & 15)] = 0.f;
            }
        }

        __syncthreads();   // barrier0
        __syncthreads();   // warmup barrier (helper idle during warmup)

        const float* xggA = &XGg[0][0][0][0];
        const float* xggB = &XGg[1][0][0][0];
        const float* amrA = &amring[0][0][0];
        const float* amrB = &amring[1][0][0];

        for (int j = 0; j < 62; ++j) {
            // outputs for previous block's steps, both batches
            if (j >= 1) {
                const int p0 = 7 + 8 * j;
                #pragma unroll
                for (int u = 0; u < 8; ++u) {
                    ROLEA(p0 + u, amrA, xggA, zoffs[0], qoffs[0]);
                    ROLEA(p0 + u, amrB, xggB, zoffs[1], qoffs[1]);
                }
            }
            const int ph = j & 7;
            // staggered refills for chunk cn = (j>>3)+1
            if ((ph == 0 && j <= 48) || (ph == 2 && j <= 50)) {
                const int bi = (ph == 0) ? 0 : 1;
                const int cn = (j >> 3) + 1;
                const int base = 14 + 64 * cn;
                const float* xb = xbp[bi];
                for (int idx = lane; idx < 66 * ND; idx += 64) {
                    int l = idx >> 3, d = idx & 7;
                    int t = base + l - 15;
                    xring[bi][idx] = (t < TLEN) ? xb[d * TLEN + t] : 0.f;
                }
            }
            if ((ph == 1 && j <= 49) || (ph == 3 && j <= 51)) {
                const int bi = (ph == 1) ? 0 : 1;
                const int cn = (j >> 3) + 1;
                const int kb = cn & 1;
                for (int i = 0; i < 64; ++i) {
                    const float4* xq = (const float4*)&xring[bi][(i + tap) * 8];
                    float4 xa = xq[0], xbv = xq[1];
                    float s0 = fmaf(wxr[0], xa.x, fmaf(wxr[1], xa.y, 0.f));
                    float s1 = fmaf(wxr[2], xa.z, fmaf(wxr[3], xa.w, 0.f));
                    float s2 = fmaf(wxr[4], xbv.x, fmaf(wxr[5], xbv.y, 0.f));
                    float s3 = fmaf(wxr[6], xbv.z, fmaf(wxr[7], xbv.w, 0.f));
                    float h = xhalfsum((s0 + s1) + (s2 + s3)) + b0r;
                    if (lane < 32) XGx[bi][kb][i][c] = h;
                }
                for (int idx = lane; idx < 64 * NK; idx += 64) {
                    int st = 64 * cn + (idx >> 3), kk = idx & 7;
                    float v = 0.f;
                    if (st < NSTEPS) {
                        float uu = ug[st * (NB * NK) + (bA + bi) * NK + kk];
                        v = -flog(-flog(uu + 1e-10f) + 1e-10f) * klog;
                    }
                    XGg[bi][kb][idx >> 3][kk] = v;
                }
            }
            __syncthreads();
        }
        // epilogue: outputs for the final block p=503..510, both batches
        #pragma unroll
        for (int u = 0; u < 8; ++u) {
            ROLEA(503 + u, amrA, xggA, zoffs[0], qoffs[0]);
            ROLEA(503 + u, amrB, xggB, zoffs[1], qoffs[1]);
        }
    }
}

extern "C" void kernel_launch(void* const* d_in, const int* in_sizes, int n_in,
                              void* d_out, int out_size, void* d_ws, size_t ws_size,
                              hipStream_t stream) {
    (void)in_sizes; (void)n_in; (void)out_size; (void)d_ws; (void)ws_size;
    regime_scan_kernel<<<dim3(NB / 2), dim3(128), 0, stream>>>(
        (const float*)d_in[0],   // x
        (const float*)d_in[1],   // temp
        (const float*)d_in[2],   // u
        (const float*)d_in[3],   // w0
        (const float*)d_in[4],   // b0
        (const float*)d_in[5],   // w1
        (const float*)d_in[6],   // b1
        (const float*)d_in[7],   // w2
        (const float*)d_in[8],   // b2
        (const float*)d_in[9],   // w3
        (const float*)d_in[10],  // b3
        (float*)d_out);
}

// Round 7
// 563.941 us; speedup vs baseline: 1.0484x; 1.0484x over previous
//
#include <hip/hip_runtime.h>

// Problem constants (from reference)
#define NB      128
#define ND      8
#define NK      8
#define TLEN    512
#define NSTEPS  496

#define INVLN2f 1.44269504088896340736f

__device__ __forceinline__ float fexp(float x) { return __expf(x); }
__device__ __forceinline__ float flog(float x) { return __logf(x); }
__device__ __forceinline__ float frcp(float x) { return __builtin_amdgcn_rcpf(x); }
__device__ __forceinline__ float elur(float x) { return x > 0.f ? x : fexp(x) - 1.f; }

#if defined(__has_builtin)
#if __has_builtin(__builtin_amdgcn_exp2f)
#define fexp2(x) __builtin_amdgcn_exp2f(x)
#endif
#endif
#ifndef fexp2
#define fexp2(x) exp2f(x)
#endif

// DPP helpers. quad_perm 0xB1 = lane^1, 0x4E = lane^2, row_ror:4 acts as lane^4
// within a replicated-every-8 value; row_ror:N (0x120|N) rotates within 16-lane rows.
// All of these are row-local (never cross 16-lane rows) => batch-safe.
#define DPP_ROR4(v) __int_as_float(__builtin_amdgcn_mov_dpp(__float_as_int(v), 0x124, 0xF, 0xF, false))
#define DPP_X1(v)   __int_as_float(__builtin_amdgcn_mov_dpp(__float_as_int(v), 0xB1, 0xF, 0xF, false))
#define DPP_X2(v)   __int_as_float(__builtin_amdgcn_mov_dpp(__float_as_int(v), 0x4E, 0xF, 0xF, false))
#define DPP_RORN(v, ctrl) __int_as_float(__builtin_amdgcn_mov_dpp(__float_as_int(v), (ctrl), 0xF, 0xF, false))

#define RED8_MAX(m) { m = fmaxf(m, DPP_X1(m)); m = fmaxf(m, DPP_X2(m)); m = fmaxf(m, DPP_ROR4(m)); }
#define RED8_SUM(s) { s = s + DPP_X1(s); s = s + DPP_X2(s); s = s + DPP_ROR4(s); }

typedef unsigned int uint2v __attribute__((ext_vector_type(2)));
typedef float floatx2 __attribute__((ext_vector_type(2)));

#define PKFMA(a, b, c) __builtin_elementwise_fma((a), (b), (c))

__device__ __forceinline__ floatx2 f2(float t) { floatx2 r; r.x = t; r.y = t; return r; }
__device__ __forceinline__ floatx2 v2(float x, float y) { floatx2 r; r.x = x; r.y = y; return r; }

#if defined(__has_builtin)
#if __has_builtin(__builtin_amdgcn_permlane16_swap)
#define HAVE_PL16SWAP 1
#endif
#endif

// Other-row value (lane^16): rows 0<->1 and 2<->3 swap, so the two 32-lane
// batches never mix. selr0 is a per-lane runtime-probed slot select.
#ifdef HAVE_PL16SWAP
#define XROW16(v) ({                                                               \
    unsigned _u = __float_as_uint(v);                                              \
    uint2v _r = __builtin_amdgcn_permlane16_swap(_u, _u, false, false);            \
    __uint_as_float(selr0 ? _r[0] : _r[1]); })
#else
#define XROW16(v) __uint_as_float((unsigned)__builtin_amdgcn_ds_swizzle(           \
                   (int)__float_as_uint(v), 0x401F))
#endif

// Full dual 32-term dot per lane (new-tap in .x, old-tap in .y). ov = own-row
// value h[16*rh + s], u0 = other-row value h[16*(1-rh) + s]. 30 row_ror DPP
// (row-local => batch-safe) + 32 pk_fma in 8 chains of 4. Weights pre-ordered
// per lane so wa[k]/wb[k] pair with rotation k of ov/u0.
__device__ __forceinline__ floatx2 dot32(float ov, float u0,
                                         const floatx2* __restrict__ wa,
                                         const floatx2* __restrict__ wb) {
    float t1 = DPP_RORN(ov, 0x121), t2 = DPP_RORN(ov, 0x122), t3 = DPP_RORN(ov, 0x123);
    float t4 = DPP_RORN(ov, 0x124), t5 = DPP_RORN(ov, 0x125), t6 = DPP_RORN(ov, 0x126);
    float t7 = DPP_RORN(ov, 0x127), t8 = DPP_RORN(ov, 0x128), t9 = DPP_RORN(ov, 0x129);
    float tA = DPP_RORN(ov, 0x12A), tB = DPP_RORN(ov, 0x12B), tC = DPP_RORN(ov, 0x12C);
    float tD = DPP_RORN(ov, 0x12D), tE = DPP_RORN(ov, 0x12E), tF = DPP_RORN(ov, 0x12F);
    float s1 = DPP_RORN(u0, 0x121), s2 = DPP_RORN(u0, 0x122), s3 = DPP_RORN(u0, 0x123);
    float s4 = DPP_RORN(u0, 0x124), s5 = DPP_RORN(u0, 0x125), s6 = DPP_RORN(u0, 0x126);
    float s7 = DPP_RORN(u0, 0x127), s8 = DPP_RORN(u0, 0x128), s9 = DPP_RORN(u0, 0x129);
    float sA = DPP_RORN(u0, 0x12A), sB = DPP_RORN(u0, 0x12B), sC = DPP_RORN(u0, 0x12C);
    float sD = DPP_RORN(u0, 0x12D), sE = DPP_RORN(u0, 0x12E), sF = DPP_RORN(u0, 0x12F);
    floatx2 a0 = wa[0] * f2(ov);
    floatx2 a1 = wa[1] * f2(t1);
    floatx2 a2 = wa[2] * f2(t2);
    floatx2 a3 = wa[3] * f2(t3);
    a0 = PKFMA(wa[4],  f2(t4), a0);  a1 = PKFMA(wa[5],  f2(t5), a1);
    a2 = PKFMA(wa[6],  f2(t6), a2);  a3 = PKFMA(wa[7],  f2(t7), a3);
    a0 = PKFMA(wa[8],  f2(t8), a0);  a1 = PKFMA(wa[9],  f2(t9), a1);
    a2 = PKFMA(wa[10], f2(tA), a2);  a3 = PKFMA(wa[11], f2(tB), a3);
    a0 = PKFMA(wa[12], f2(tC), a0);  a1 = PKFMA(wa[13], f2(tD), a1);
    a2 = PKFMA(wa[14], f2(tE), a2);  a3 = PKFMA(wa[15], f2(tF), a3);
    floatx2 c0 = wb[0] * f2(u0);
    floatx2 c1 = wb[1] * f2(s1);
    floatx2 c2 = wb[2] * f2(s2);
    floatx2 c3 = wb[3] * f2(s3);
    c0 = PKFMA(wb[4],  f2(s4), c0);  c1 = PKFMA(wb[5],  f2(s5), c1);
    c2 = PKFMA(wb[6],  f2(s6), c2);  c3 = PKFMA(wb[7],  f2(s7), c3);
    c0 = PKFMA(wb[8],  f2(s8), c0);  c1 = PKFMA(wb[9],  f2(s9), c1);
    c2 = PKFMA(wb[10], f2(sA), c2);  c3 = PKFMA(wb[11], f2(sB), c3);
    c0 = PKFMA(wb[12], f2(sC), c0);  c1 = PKFMA(wb[13], f2(sD), c1);
    c2 = PKFMA(wb[14], f2(sE), c2);  c3 = PKFMA(wb[15], f2(sF), c3);
    return ((a0 + a1) + (a2 + a3)) + ((c0 + c1) + (c2 + c3));
}

// One scan step for BOTH batches (lanes 0-31 = A, 32-63 = B): every
// instruction serves both. Full dots -> no halfsum, full biases in parks.
#define STEP(qv, S1, S2, S3, DO_OUT)                                              \
  {                                                                               \
    const int q_ = (qv);                                                          \
    float o0v = elur(XZ);                                                         \
    float x0 = XROW16(o0v);                                                       \
    floatx2 d1 = dot32(o0v, x0, w1a, w1b);                                        \
    float o1v = elur(d1.x + P1[S1]);                                              \
    P1[S1] = b1r + d1.y;                                                          \
    float x1 = XROW16(o1v);                                                       \
    floatx2 d2 = dot32(o1v, x1, w2a, w2b);                                        \
    float o2v = elur(d2.x + P2[S2]);                                              \
    P2[S2] = b2r + d2.y;                                                          \
    float x2 = XROW16(o2v);                                                       \
    floatx2 d3 = dot32(o2v, x2, w3a, w3b);                                        \
    float a3m = elur(d3.x + P3[S3]);                                              \
    P3[S3] = b3r + d3.y;                                                          \
    if (DO_OUT) {                                                                 \
      float g2 = gls2[h][(q_ - 15) & 127][o3];                                    \
      float F = fexp2(fmaf(a3m, klog, g2));                                       \
      float rt1 = DPP_RORN(F, 0x121), rt2 = DPP_RORN(F, 0x122);                   \
      float rt3 = DPP_RORN(F, 0x123), rt4 = DPP_RORN(F, 0x124);                   \
      float rt5 = DPP_RORN(F, 0x125), rt6 = DPP_RORN(F, 0x126);                   \
      float rt7 = DPP_RORN(F, 0x127);                                             \
      float S = ((F + rt1) + (rt2 + rt3)) + ((rt4 + rt5) + (rt6 + rt7));          \
      float r2 = frcp(S);                                                         \
      floatx2 na = wz[0] * f2(F),   nb = wz[1] * f2(rt1);                         \
      floatx2 nc = wz[2] * f2(rt2), nd = wz[3] * f2(rt3);                         \
      na = PKFMA(wz[4], f2(rt4), na); nb = PKFMA(wz[5], f2(rt5), nb);             \
      nc = PKFMA(wz[6], f2(rt6), nc); nd = PKFMA(wz[7], f2(rt7), nd);             \
      floatx2 zacc = (na + nb) + (nc + nd);                                       \
      ZN   = zacc.x * r2;                                                         \
      ZQ2n = zacc.y * r2;                                                         \
      /* off-path: log-softmax output (max-sub kept: overflow-safe) */            \
      float mx = a3m; RED8_MAX(mx);                                               \
      float e = fexp(a3m - mx);                                                   \
      float se = e; RED8_SUM(se);                                                 \
      float lse = mx + flog(se);                                                  \
      if (l32 < 8) {                                                              \
        outg[zoffh + o3 * TLEN + q_ + 1]       = F * r2;                          \
        outg[qoffh + o3 * NSTEPS + (q_ - 15)]  = a3m - lse;                       \
      }                                                                           \
    }                                                                             \
    /* park x-part + z-feedback for step q_+1 */                                  \
    {                                                                             \
      const float4* xq0 = (const float4*)&xcol2[h][q_][0];                        \
      float4 xa = xq0[0], xb4 = xq0[1];                                           \
      const float4* xq1 = (const float4*)&xcol2[h][q_ + 1][0];                    \
      float4 xc = xq1[0], xd4 = xq1[1];                                           \
      floatx2 p0 = wxp[0][0] * v2(xa.x, xa.y);                                    \
      p0 = PKFMA(wxp[0][1], v2(xa.z, xa.w), p0);                                  \
      p0 = PKFMA(wxp[0][2], v2(xb4.x, xb4.y), p0);                                \
      p0 = PKFMA(wxp[0][3], v2(xb4.z, xb4.w), p0);                                \
      floatx2 p1 = wxp[1][0] * v2(xc.x, xc.y);                                    \
      p1 = PKFMA(wxp[1][1], v2(xc.z, xc.w), p1);                                  \
      p1 = PKFMA(wxp[1][2], v2(xd4.x, xd4.y), p1);                                \
      p1 = PKFMA(wxp[1][3], v2(xd4.z, xd4.w), p1);                                \
      floatx2 pp = p0 + p1;                                                       \
      XZ = (((pp.x + pp.y) + b0r) + ZQ2) + ZN;                                    \
      ZQ2 = ZQ2n;                                                                 \
    }                                                                             \
  }

__global__ __launch_bounds__(64, 1)
void regime_scan_kernel(const float* __restrict__ xg,
                        const float* __restrict__ tempg,
                        const float* __restrict__ ug,
                        const float* __restrict__ w0g,
                        const float* __restrict__ b0g,
                        const float* __restrict__ w1g,
                        const float* __restrict__ b1g,
                        const float* __restrict__ w2g,
                        const float* __restrict__ b2g,
                        const float* __restrict__ w3g,
                        const float* __restrict__ b3g,
                        float* __restrict__ outg)
{
    // Single wave owns 2 batches: no barriers anywhere.
    __shared__ __align__(16) float xcol2[2][527][8];    // 33.7 KB (full x window)
    __shared__ __align__(16) float gls2[2][128][8];     // 8 KB (g2 ring, 128 steps)

    const int lane = threadIdx.x;
    const int h    = lane >> 5;            // batch half (0=A, 1=B)
    const int l32  = lane & 31;
    const int c    = lane & 31;            // channel owned within batch
    const int o3   = lane & 7;             // layer-3 / regime channel
    const int s    = lane & 15;            // slot within 16-lane DPP row
    const int rh   = (lane >> 4) & 1;      // row within batch half
    const int bh   = blockIdx.x * 2 + h;   // this half's batch index

    // ---- runtime probe (uniform): row_ror direction on this HW ----
    int dir;
    {
        int l15 = lane & 15;
        int rr1 = __builtin_amdgcn_mov_dpp(l15, 0x121, 0xF, 0xF, false);
        dir = (rr1 == ((l15 + 1) & 15)) ? 1 : -1;
    }
    // ---- runtime probe (per-lane): which permlane16_swap slot is lane^16 ----
    int selr0 = 0;
#ifdef HAVE_PL16SWAP
    {
        unsigned li = (unsigned)lane;
        uint2v pr = __builtin_amdgcn_permlane16_swap(li, li, false, false);
        selr0 = (pr[0] == (li ^ 16u)) ? 1 : 0;
    }
#endif
    (void)selr0;

    // ---- per-lane weights: rotation-ordered, dual (new=.x, old=.y) ----
    // A-side: own row channels 16*rh + ((s+dir*k)&15); B-side: other row.
    floatx2 w1a[16], w1b[16], w2a[16], w2b[16], w3a[16], w3b[16];
    #pragma unroll
    for (int k = 0; k < 16; ++k) {
        int jA = 16 * rh       + ((s + dir * k) & 15);
        int jB = 16 * (1 - rh) + ((s + dir * k) & 15);
        w1a[k].x = w1g[c  * 64 + jA * 2 + 1]; w1a[k].y = w1g[c  * 64 + jA * 2 + 0];
        w1b[k].x = w1g[c  * 64 + jB * 2 + 1]; w1b[k].y = w1g[c  * 64 + jB * 2 + 0];
        w2a[k].x = w2g[c  * 64 + jA * 2 + 1]; w2a[k].y = w2g[c  * 64 + jA * 2 + 0];
        w2b[k].x = w2g[c  * 64 + jB * 2 + 1]; w2b[k].y = w2g[c  * 64 + jB * 2 + 0];
        w3a[k].x = w3g[o3 * 64 + jA * 2 + 1]; w3a[k].y = w3g[o3 * 64 + jA * 2 + 0];
        w3b[k].x = w3g[o3 * 64 + jB * 2 + 1]; w3b[k].y = w3g[o3 * 64 + jB * 2 + 0];
    }
    // layer0 z weights, 8-group rotation order, dual (new=.x, old=.y)
    floatx2 wz[8];
    #pragma unroll
    for (int r = 0; r < 8; ++r) {
        int ch = (o3 + dir * r) & 7;
        wz[r].x = w0g[c * 32 + (8 + ch) * 2 + 1];
        wz[r].y = w0g[c * 32 + (8 + ch) * 2 + 0];
    }
    // layer0 x weights: [tap][dim-pair] packed
    floatx2 wxp[2][4];
    #pragma unroll
    for (int t = 0; t < 2; ++t)
        #pragma unroll
        for (int di = 0; di < 4; ++di) {
            wxp[t][di].x = w0g[c * 32 + (2 * di)     * 2 + t];
            wxp[t][di].y = w0g[c * 32 + (2 * di + 1) * 2 + t];
        }
    const float b0r = b0g[c];
    const float b1r = b1g[c];
    const float b2r = b2g[c];
    const float b3r = b3g[o3];
    const float klog = frcp(tempg[0]) * INVLN2f;

    // ---- prologue (each 32-lane half loads its own batch) ----
    const float* xb = xg + bh * (ND * TLEN);
    if (l32 < 15) {
        #pragma unroll
        for (int d = 0; d < ND; ++d) xcol2[h][l32][d] = 0.f;
    }
    for (int t = l32; t < TLEN; t += 32) {
        #pragma unroll
        for (int d = 0; d < ND; ++d) xcol2[h][15 + t][d] = xb[d * TLEN + t];
    }
    for (int idx = l32; idx < 128 * NK; idx += 32) {
        int st = idx >> 3, kk = idx & 7;
        float uu = ug[st * (NB * NK) + bh * NK + kk];
        gls2[h][idx >> 3][kk] = -flog(-flog(uu + 1e-10f) + 1e-10f) * klog;
    }
    const int zoffh = bh * (NK * TLEN);
    const int qoffh = NB * NK * TLEN + bh * (NK * NSTEPS);
    for (int idx = l32; idx < NK * 16; idx += 32) {
        outg[zoffh + (idx >> 4) * TLEN + (idx & 15)] = 0.f;
    }

    // ---- state ----
    float P1[2] = { b1r, b1r };
    float P2[4] = { b2r, b2r, b2r, b2r };
    float P3[8];
    #pragma unroll
    for (int k = 0; k < 8; ++k) P3[k] = b3r;
    float ZQ2 = 0.f, ZQ2n = 0.f, ZN = 0.f;
    float XZ;
    {   // XP(1) from cols 0,1 (z = 0 at start)
        const float4* xq0 = (const float4*)&xcol2[h][0][0];
        float4 xa = xq0[0], xb4 = xq0[1];
        const float4* xq1 = (const float4*)&xcol2[h][1][0];
        float4 xc = xq1[0], xd4 = xq1[1];
        floatx2 p0 = wxp[0][0] * v2(xa.x, xa.y);
        p0 = PKFMA(wxp[0][1], v2(xa.z, xa.w), p0);
        p0 = PKFMA(wxp[0][2], v2(xb4.x, xb4.y), p0);
        p0 = PKFMA(wxp[0][3], v2(xb4.z, xb4.w), p0);
        floatx2 p1 = wxp[1][0] * v2(xc.x, xc.y);
        p1 = PKFMA(wxp[1][1], v2(xc.z, xc.w), p1);
        p1 = PKFMA(wxp[1][2], v2(xd4.x, xd4.y), p1);
        p1 = PKFMA(wxp[1][3], v2(xd4.z, xd4.w), p1);
        floatx2 pp = p0 + p1;
        XZ = (pp.x + pp.y) + b0r;
    }

    // ---- warmup q=1..14 (no outputs, feedback zero) ----
    #pragma unroll
    for (int q = 1; q <= 14; ++q) STEP(q, q & 1, q & 3, q & 7, 0);

    // ---- main: 4 chunks of <=128 steps; per-wave g2 ring refill ----
    for (int n = 0; n < 4; ++n) {
        if (n > 0) {
            for (int idx = l32; idx < 128 * NK; idx += 32) {
                int st = 128 * n + (idx >> 3), kk = idx & 7;
                float v = 0.f;
                if (st < NSTEPS) {
                    float uu = ug[st * (NB * NK) + bh * NK + kk];
                    v = -flog(-flog(uu + 1e-10f) + 1e-10f) * klog;
                }
                gls2[h][idx >> 3][kk] = v;
            }
        }
        const int jmax = (n < 3) ? 16 : 14;   // 496 = 3*128 + 112
        const int qb0 = 15 + 128 * n;
        for (int j = 0; j < jmax; ++j) {
            const int qb = qb0 + 8 * j;
            #pragma unroll
            for (int uu = 0; uu < 8; ++uu) {
                STEP(qb + uu, (15 + uu) & 1, (15 + uu) & 3, (15 + uu) & 7, 1);
            }
        }
    }
}

extern "C" void kernel_launch(void* const* d_in, const int* in_sizes, int n_in,
                              void* d_out, int out_size, void* d_ws, size_t ws_size,
                              hipStream_t stream) {
    (void)in_sizes; (void)n_in; (void)out_size; (void)d_ws; (void)ws_size;
    regime_scan_kernel<<<dim3(NB / 2), dim3(64), 0, stream>>>(
        (const float*)d_in[0],   // x
        (const float*)d_in[1],   // temp
        (const float*)d_in[2],   // u
        (const float*)d_in[3],   // w0
        (const float*)d_in[4],   // b0
        (const float*)d_in[5],   // w1
        (const float*)d_in[6],   // b1
        (const float*)d_in[7],   // w2
        (const float*)d_in[8],   // b2
        (const float*)d_in[9],   // w3
        (const float*)d_in[10],  // b3
        (float*)d_out);
}

// Round 8
// 350.737 us; speedup vs baseline: 1.6856x; 1.6079x over previous
//
#include <hip/hip_runtime.h>

// Problem constants (from reference)
#define NB      128
#define ND      8
#define NK      8
#define TLEN    512
#define NSTEPS  496

#define INVLN2f 1.44269504088896340736f

__device__ __forceinline__ float fexp(float x) { return __expf(x); }
__device__ __forceinline__ float flog(float x) { return __logf(x); }
__device__ __forceinline__ float frcp(float x) { return __builtin_amdgcn_rcpf(x); }
__device__ __forceinline__ float elur(float x) { return x > 0.f ? x : fexp(x) - 1.f; }

#if defined(__has_builtin)
#if __has_builtin(__builtin_amdgcn_exp2f)
#define fexp2(x) __builtin_amdgcn_exp2f(x)
#endif
#endif
#ifndef fexp2
#define fexp2(x) exp2f(x)
#endif

// DPP helpers. quad_perm 0xB1 = lane^1, 0x4E = lane^2, row_ror:4 acts as lane^4
// within a replicated-every-8 value; row_ror:N (0x120|N) rotates within 16-lane rows.
#define DPP_ROR4(v) __int_as_float(__builtin_amdgcn_mov_dpp(__float_as_int(v), 0x124, 0xF, 0xF, false))
#define DPP_X1(v)   __int_as_float(__builtin_amdgcn_mov_dpp(__float_as_int(v), 0xB1, 0xF, 0xF, false))
#define DPP_X2(v)   __int_as_float(__builtin_amdgcn_mov_dpp(__float_as_int(v), 0x4E, 0xF, 0xF, false))
#define DPP_RORN(v, ctrl) __int_as_float(__builtin_amdgcn_mov_dpp(__float_as_int(v), (ctrl), 0xF, 0xF, false))

#define RED8_MAX(m) { m = fmaxf(m, DPP_X1(m)); m = fmaxf(m, DPP_X2(m)); m = fmaxf(m, DPP_ROR4(m)); }
#define RED8_SUM(s) { s = s + DPP_X1(s); s = s + DPP_X2(s); s = s + DPP_ROR4(s); }

typedef unsigned int uint2v __attribute__((ext_vector_type(2)));
typedef float floatx2 __attribute__((ext_vector_type(2)));

#define PKFMA(a, b, c) __builtin_elementwise_fma((a), (b), (c))

__device__ __forceinline__ floatx2 f2(float t) { floatx2 r; r.x = t; r.y = t; return r; }

// v + v[lane^32] on all lanes, via VALU permlane32_swap (no DS pipe).
#if defined(__has_builtin)
#if __has_builtin(__builtin_amdgcn_permlane32_swap)
#define HAVE_PLSWAP 1
#endif
#if __has_builtin(__builtin_amdgcn_permlane16_swap)
#define HAVE_PL16SWAP 1
#endif
#endif

#ifdef HAVE_PLSWAP
__device__ __forceinline__ float xhalfsum(float v) {
    unsigned int u = __float_as_uint(v);
    uint2v r = __builtin_amdgcn_permlane32_swap(u, u, false, false);
    return __uint_as_float(r[0]) + __uint_as_float(r[1]);
}
#else
__device__ __forceinline__ float xhalfsum(float v) { return v + __shfl_xor(v, 32); }
#endif

// Layout-B fixup: rows 0,1 (lanes 0-31) keep own value; rows 2,3 take lane^16's.
#ifdef HAVE_PL16SWAP
#define TOB(v) ({                                                                  \
    float _v = (v);                                                                \
    unsigned _u = __float_as_uint(_v);                                             \
    uint2v _r = __builtin_amdgcn_permlane16_swap(_u, _u, false, false);            \
    float _o = __uint_as_float(selr0 ? _r[0] : _r[1]);                             \
    (lane < 32) ? _v : _o; })
#else
#define TOB(v) ({                                                                  \
    float _v = (v);                                                                \
    float _o = __uint_as_float((unsigned)__builtin_amdgcn_ds_swizzle(              \
                   (int)__float_as_uint(_v), 0x401F));                             \
    (lane < 32) ? _v : _o; })
#endif

// Dual 16-term rotation dot (new-tap in .x, old-tap in .y). vB holds, at row
// slot s, h[jbase+s]; the 15 row_ror DPP movs are independent (all off vB).
// Weights pre-ordered per lane so wp[r] pairs with rotation r.
__device__ __forceinline__ floatx2 rotdot16x2p(float vB, const floatx2* __restrict__ wp) {
    float t1 = DPP_RORN(vB, 0x121), t2 = DPP_RORN(vB, 0x122), t3 = DPP_RORN(vB, 0x123);
    float t4 = DPP_RORN(vB, 0x124), t5 = DPP_RORN(vB, 0x125), t6 = DPP_RORN(vB, 0x126);
    float t7 = DPP_RORN(vB, 0x127), t8 = DPP_RORN(vB, 0x128), t9 = DPP_RORN(vB, 0x129);
    float tA = DPP_RORN(vB, 0x12A), tB = DPP_RORN(vB, 0x12B), tC = DPP_RORN(vB, 0x12C);
    float tD = DPP_RORN(vB, 0x12D), tE = DPP_RORN(vB, 0x12E), tF = DPP_RORN(vB, 0x12F);
    floatx2 a0 = wp[0] * f2(vB);
    floatx2 a1 = wp[1] * f2(t1);
    floatx2 a2 = wp[2] * f2(t2);
    floatx2 a3 = wp[3] * f2(t3);
    a0 = PKFMA(wp[4],  f2(t4), a0);
    a1 = PKFMA(wp[5],  f2(t5), a1);
    a2 = PKFMA(wp[6],  f2(t6), a2);
    a3 = PKFMA(wp[7],  f2(t7), a3);
    a0 = PKFMA(wp[8],  f2(t8), a0);
    a1 = PKFMA(wp[9],  f2(t9), a1);
    a2 = PKFMA(wp[10], f2(tA), a2);
    a3 = PKFMA(wp[11], f2(tB), a3);
    a0 = PKFMA(wp[12], f2(tC), a0);
    a1 = PKFMA(wp[13], f2(tD), a1);
    a2 = PKFMA(wp[14], f2(tE), a2);
    a3 = PKFMA(wp[15], f2(tF), a3);
    return (a0 + a1) + (a2 + a3);
}

// One scan step. All per-step LDS reads (next x cols, next g2) are PREFETCHED
// one full step ahead into registers (cxa/cxb/G2R), so no lgkm wait is ever on
// the critical chain. XBASE (x-part of XZ(q+1)) is computed at step START from
// already-available registers; the feedback tail only does XZ = XBASE + ZN.
// PREFG: whether to prefetch g2 for q+1 (only valid from q=14 on).
#define STEP(qv, S1, S2, S3, DO_OUT, PREFG)                                       \
  {                                                                               \
    const int q_ = (qv);                                                          \
    /* prefetch next step's LDS data (latency hidden under this step) */          \
    const float4* _nx = (const float4*)&xcol[q_ + 1 + tap][0];                    \
    float4 nxa = _nx[0], nxb = _nx[1];                                            \
    float g2n = 0.f;                                                              \
    if (PREFG) g2n = gls[(q_ - 14) * NK + o3];                                    \
    /* early: x-base of XZ(q_+1) from regs prefetched last step */                \
    float s0 = fmaf(wxr[0], cxa.x, fmaf(wxr[1], cxa.y, 0.f));                     \
    float s1 = fmaf(wxr[2], cxa.z, fmaf(wxr[3], cxa.w, 0.f));                     \
    float s2 = fmaf(wxr[4], cxb.x, fmaf(wxr[5], cxb.y, 0.f));                     \
    float s3 = fmaf(wxr[6], cxb.z, fmaf(wxr[7], cxb.w, 0.f));                     \
    float XBASE = (xhalfsum((s0 + s1) + (s2 + s3)) + b0r) + ZQ2;                  \
    /* layer 0: all contributions pre-folded into XZ */                           \
    float o0v = elur(XZ);                                                         \
    /* layer 1 */                                                                 \
    float v0B = TOB(o0v);                                                         \
    floatx2 d1 = rotdot16x2p(v0B, w1p);                                           \
    float o1v = elur(xhalfsum(d1.x + P1[S1]));                                    \
    P1[S1] = b1h + d1.y;                                                          \
    /* layer 2 */                                                                 \
    float v1B = TOB(o1v);                                                         \
    floatx2 d2 = rotdot16x2p(v1B, w2p);                                           \
    float o2v = elur(xhalfsum(d2.x + P2[S2]));                                    \
    P2[S2] = b2h + d2.y;                                                          \
    /* layer 3 */                                                                 \
    float v2B = TOB(o2v);                                                         \
    floatx2 d3 = rotdot16x2p(v2B, w3p);                                           \
    float a3m = elur(xhalfsum(d3.x + P3[S3]));                                    \
    P3[S3] = b3h + d3.y;                                                          \
    if (DO_OUT) {                                                                 \
      /* feedback gumbel-softmax: single exp2, no max-sub */                      \
      float F = fexp2(fmaf(a3m, klog, G2R));                                      \
      float rt1 = DPP_RORN(F, 0x121), rt2 = DPP_RORN(F, 0x122);                   \
      float rt3 = DPP_RORN(F, 0x123), rt4 = DPP_RORN(F, 0x124);                   \
      float rt5 = DPP_RORN(F, 0x125), rt6 = DPP_RORN(F, 0x126);                   \
      float rt7 = DPP_RORN(F, 0x127);                                             \
      float S = ((F + rt1) + (rt2 + rt3)) + ((rt4 + rt5) + (rt6 + rt7));          \
      float r2 = frcp(S);                                                         \
      floatx2 na = wz[0] * f2(F),   nb = wz[1] * f2(rt1);                         \
      floatx2 nc = wz[2] * f2(rt2), nd = wz[3] * f2(rt3);                         \
      na = PKFMA(wz[4], f2(rt4), na); nb = PKFMA(wz[5], f2(rt5), nb);             \
      nc = PKFMA(wz[6], f2(rt6), nc); nd = PKFMA(wz[7], f2(rt7), nd);             \
      floatx2 zacc = (na + nb) + (nc + nd);                                       \
      ZN   = zacc.x * r2;   /* wzn.y(q) -> XZ at q+1 */                           \
      ZQ2n = zacc.y * r2;   /* wzo.y(q) -> XZ at q+2 */                           \
      /* off-path: log-softmax output (fills stall slots) */                      \
      float mx = a3m; RED8_MAX(mx);                                               \
      float e = fexp(a3m - mx);                                                   \
      float se = e; RED8_SUM(se);                                                 \
      float lse = mx + flog(se);                                                  \
      if (lane < 8) {                                                             \
        outg[zoff + lane * TLEN + q_ + 1]       = F * r2;                         \
        outg[qoff + lane * NSTEPS + (q_ - 15)]  = a3m - lse;                      \
      }                                                                           \
    }                                                                             \
    /* feedback tail: single add; rotate state; latch prefetches */               \
    XZ = XBASE + ZN;                                                              \
    ZQ2 = ZQ2n;                                                                   \
    cxa = nxa; cxb = nxb; G2R = g2n;                                              \
  }

__global__ __launch_bounds__(64, 1)
void regime_scan_kernel(const float* __restrict__ xg,
                        const float* __restrict__ tempg,
                        const float* __restrict__ ug,
                        const float* __restrict__ w0g,
                        const float* __restrict__ b0g,
                        const float* __restrict__ w1g,
                        const float* __restrict__ b1g,
                        const float* __restrict__ w2g,
                        const float* __restrict__ b2g,
                        const float* __restrict__ w3g,
                        const float* __restrict__ b3g,
                        float* __restrict__ outg)
{
    __shared__ __align__(16) float xcol[527][8];           // 16.9 KB
    __shared__ __align__(16) float gls[NSTEPS * NK + 8];   // 15.9 KB (g2, padded)

    const int lane = threadIdx.x;
    const int b    = blockIdx.x;
    const int c    = lane & 31;            // channel owned (layers 0-2)
    const int o3   = lane & 7;             // layer-3 channel owned
    const int tap  = (lane < 32) ? 1 : 0;  // x-park tap role
    const int s    = lane & 15;            // slot within 16-lane DPP row
    const int rowq = lane >> 4;            // DPP row 0..3
    // rows hold j-halves [lo,hi,hi,lo] after the TOB fixup
    const int jbase = ((rowq ^ (rowq >> 1)) & 1) << 4;

    // ---- runtime probe (uniform): row_ror direction on this HW ----
    int dir;
    {
        int l15 = lane & 15;
        int rr1 = __builtin_amdgcn_mov_dpp(l15, 0x121, 0xF, 0xF, false); // row_ror:1
        dir = (rr1 == ((l15 + 1) & 15)) ? 1 : -1;
    }
    // ---- runtime probe (per-lane): which permlane16_swap slot is lane^16 ----
    int selr0 = 0;
#ifdef HAVE_PL16SWAP
    {
        unsigned li = (unsigned)lane;
        uint2v pr = __builtin_amdgcn_permlane16_swap(li, li, false, false);
        selr0 = (pr[0] == (li ^ 16u)) ? 1 : 0;
    }
#endif
    (void)selr0;

    // ---- per-lane weights ----
    // layer0 z weights in 8-group ROTATION order, packed (new=.x, old=.y)
    floatx2 wz[8];
    #pragma unroll
    for (int r = 0; r < 8; ++r) {
        int ch = (o3 + dir * r) & 7;
        wz[r].x = w0g[c * 32 + (8 + ch) * 2 + 1];
        wz[r].y = w0g[c * 32 + (8 + ch) * 2 + 0];
    }
    float wxr[8];
    #pragma unroll
    for (int d = 0; d < 8; ++d) wxr[d] = w0g[c * 32 + d * 2 + tap];
    // layers 1-3: dual (new,old) weights in 16-row ROTATION order
    floatx2 w1p[16], w2p[16], w3p[16];
    #pragma unroll
    for (int r = 0; r < 16; ++r) {
        int jj = jbase + ((s + dir * r) & 15);
        w1p[r].x = w1g[c  * 64 + jj * 2 + 1];
        w1p[r].y = w1g[c  * 64 + jj * 2 + 0];
        w2p[r].x = w2g[c  * 64 + jj * 2 + 1];
        w2p[r].y = w2g[c  * 64 + jj * 2 + 0];
        w3p[r].x = w3g[o3 * 64 + jj * 2 + 1];
        w3p[r].y = w3g[o3 * 64 + jj * 2 + 0];
    }
    const float b0r  = b0g[c];
    const float b1h  = 0.5f * b1g[c];      // half-bias: completed by xhalfsum
    const float b2h  = 0.5f * b2g[c];
    const float b3h  = 0.5f * b3g[o3];
    const float tinv = frcp(tempg[0]);
    const float klog = tinv * INVLN2f;     // a3 coefficient in exp2 domain

    // ---- prologue: x columns ----
    if (lane < 15) {
        #pragma unroll
        for (int d = 0; d < ND; ++d) xcol[lane][d] = 0.f;
    }
    const float* xb = xg + b * (ND * TLEN);
    for (int t = lane; t < TLEN; t += 64) {
        #pragma unroll
        for (int d = 0; d < ND; ++d) xcol[15 + t][d] = xb[d * TLEN + t];
    }
    // ---- prologue: Gumbel noise, pre-scaled: g2 = g * tinv / ln2 ----
    for (int idx = lane; idx < NSTEPS * NK; idx += 64) {
        int st = idx >> 3, k = idx & 7;
        float uu = ug[st * (NB * NK) + b * NK + k];
        float g  = -flog(-flog(uu + 1e-10f) + 1e-10f);
        gls[idx] = g * klog;
    }
    // ---- z_all[:, :, 0:16] = 0 ----
    const int zoff = b * (NK * TLEN);
    const int qoff = NB * NK * TLEN + b * (NK * NSTEPS);
    for (int idx = lane; idx < NK * 16; idx += 64) {
        outg[zoff + (idx >> 4) * TLEN + (idx & 15)] = 0.f;
    }

    // ---- state ----
    float P1[2] = { b1h, b1h };
    float P2[4] = { b2h, b2h, b2h, b2h };
    float P3[8];
    #pragma unroll
    for (int k = 0; k < 8; ++k) P3[k] = b3h;
    float ZQ2 = 0.f, ZQ2n = 0.f, ZN = 0.f;
    float G2R = 0.f;
    float XZ;
    {
        const float4* xq = (const float4*)&xcol[tap][0];
        float4 xa = xq[0], xbv = xq[1];
        float s0 = fmaf(wxr[0], xa.x, fmaf(wxr[1], xa.y, 0.f));
        float s1 = fmaf(wxr[2], xa.z, fmaf(wxr[3], xa.w, 0.f));
        float s2 = fmaf(wxr[4], xbv.x, fmaf(wxr[5], xbv.y, 0.f));
        float s3 = fmaf(wxr[6], xbv.z, fmaf(wxr[7], xbv.w, 0.f));
        XZ = xhalfsum((s0 + s1) + (s2 + s3)) + b0r;   // z = 0 at start
    }
    // prefetch registers for STEP(1)'s park: xcol[1+tap]
    float4 cxa, cxb;
    {
        const float4* cx = (const float4*)&xcol[1 + tap][0];
        cxa = cx[0]; cxb = cx[1];
    }

    // ---- warmup q=1..14 (z stays zero; g2 prefetch only at q=14) ----
    #pragma unroll
    for (int q = 1; q <= 14; ++q) STEP(q, q & 1, q & 3, q & 7, 0, (q == 14));

    // ---- main loop q=15..510, unrolled by 8 ----
    for (int qb = 15; qb <= 503; qb += 8) {
        #pragma unroll
        for (int u = 0; u < 8; ++u) {
            STEP(qb + u, (15 + u) & 1, (15 + u) & 3, (15 + u) & 7, 1, 1);
        }
    }
}

extern "C" void kernel_launch(void* const* d_in, const int* in_sizes, int n_in,
                              void* d_out, int out_size, void* d_ws, size_t ws_size,
                              hipStream_t stream) {
    (void)in_sizes; (void)n_in; (void)out_size; (void)d_ws; (void)ws_size;
    regime_scan_kernel<<<dim3(NB), dim3(64), 0, stream>>>(
        (const float*)d_in[0],   // x
        (const float*)d_in[1],   // temp
        (const float*)d_in[2],   // u
        (const float*)d_in[3],   // w0
        (const float*)d_in[4],   // b0
        (const float*)d_in[5],   // w1
        (const float*)d_in[6],   // b1
        (const float*)d_in[7],   // w2
        (const float*)d_in[8],   // b2
        (const float*)d_in[9],   // w3
        (const float*)d_in[10],  // b3
        (float*)d_out);
}